// Round 2
// baseline (39.068 us; speedup 1.0000x reference)
//
#include <hip/hip_runtime.h>

#define HW 512
#define NB 8

__device__ __forceinline__ float prelu(float x, float a) { return x >= 0.f ? x : a * x; }

// K1: compute s = i1 + i2 + i3, write to s_out (= d_out), emit per-block partial sums.
__global__ __launch_bounds__(256) void k1_compute_s(
    const float* __restrict__ in1, const float* __restrict__ in2, const float* __restrict__ in3,
    const float* __restrict__ Wd, const float* __restrict__ bd, const float* __restrict__ ad,
    const float* __restrict__ Wu, const float* __restrict__ bu, const float* __restrict__ au,
    float* __restrict__ s_out, float* __restrict__ partials)
{
    const int b  = blockIdx.z;
    const int h0 = blockIdx.y * 16, w0 = blockIdx.x * 16;
    const int tid = threadIdx.x;

    __shared__ float d1[17][17][3];

    // Stage d1 tile: d1(h,w) = prelu(input1[2h,2w,:] @ W_down + b_down)
    for (int idx = tid; idx < 17 * 17; idx += 256) {
        const int ty = idx / 17, tx = idx % 17;
        const int gh = h0 + ty, gw = w0 + tx;
        float v0 = -INFINITY, v1 = -INFINITY, v2 = -INFINITY;
        if (gh < HW && gw < HW) {
            const float* p = in1 + (((b * 1024 + 2 * gh) * 1024 + 2 * gw) * 3);
            const float x0 = p[0], x1 = p[1], x2 = p[2];
            v0 = prelu(x0 * Wd[0] + x1 * Wd[3] + x2 * Wd[6] + bd[0], ad[0]);
            v1 = prelu(x0 * Wd[1] + x1 * Wd[4] + x2 * Wd[7] + bd[1], ad[1]);
            v2 = prelu(x0 * Wd[2] + x1 * Wd[5] + x2 * Wd[8] + bd[2], ad[2]);
        }
        d1[ty][tx][0] = v0; d1[ty][tx][1] = v1; d1[ty][tx][2] = v2;
    }
    __syncthreads();

    const int ty = tid >> 4, tx = tid & 15;
    const int h = h0 + ty, w = w0 + tx;

    // i1: 2x2 window max over d1 (OOR entries are -inf)
    float i1c0 = fmaxf(fmaxf(d1[ty][tx][0], d1[ty][tx + 1][0]),
                       fmaxf(d1[ty + 1][tx][0], d1[ty + 1][tx + 1][0]));
    float i1c1 = fmaxf(fmaxf(d1[ty][tx][1], d1[ty][tx + 1][1]),
                       fmaxf(d1[ty + 1][tx][1], d1[ty + 1][tx + 1][1]));
    float i1c2 = fmaxf(fmaxf(d1[ty][tx][2], d1[ty][tx + 1][2]),
                       fmaxf(d1[ty + 1][tx][2], d1[ty + 1][tx + 1][2]));

    // i3: max(c_up, conv at the unique even-even window position, if in range)
    const float cu0 = prelu(bu[0], au[0]);
    const float cu1 = prelu(bu[1], au[1]);
    const float cu2 = prelu(bu[2], au[2]);
    float i3c0 = cu0, i3c1 = cu1, i3c2 = cu2;
    const int he = h + (h & 1), we = w + (w & 1);
    if (he < HW && we < HW) {
        const float* p = in3 + (((b * 256 + (he >> 1)) * 256 + (we >> 1)) * 3);
        const float x0 = p[0], x1 = p[1], x2 = p[2];
        i3c0 = fmaxf(i3c0, prelu(x0 * Wu[0] + x1 * Wu[3] + x2 * Wu[6] + bu[0], au[0]));
        i3c1 = fmaxf(i3c1, prelu(x0 * Wu[1] + x1 * Wu[4] + x2 * Wu[7] + bu[1], au[1]));
        i3c2 = fmaxf(i3c2, prelu(x0 * Wu[2] + x1 * Wu[5] + x2 * Wu[8] + bu[2], au[2]));
    }

    // i2 + sum
    const int pix = ((b * HW + h) * HW + w) * 3;
    float s0 = i1c0 + in2[pix + 0] + i3c0;
    float s1 = i1c1 + in2[pix + 1] + i3c1;
    float s2 = i1c2 + in2[pix + 2] + i3c2;

    s_out[pix + 0] = s0; s_out[pix + 1] = s1; s_out[pix + 2] = s2;

    // deterministic block reduction of (s0,s1,s2)
    #pragma unroll
    for (int off = 32; off > 0; off >>= 1) {
        s0 += __shfl_down(s0, off);
        s1 += __shfl_down(s1, off);
        s2 += __shfl_down(s2, off);
    }
    __shared__ float red[4][3];
    const int lane = tid & 63, wave = tid >> 6;
    if (lane == 0) { red[wave][0] = s0; red[wave][1] = s1; red[wave][2] = s2; }
    __syncthreads();
    if (tid == 0) {
        const int pid = (b * 32 + blockIdx.y) * 32 + blockIdx.x;
        partials[pid * 3 + 0] = red[0][0] + red[1][0] + red[2][0] + red[3][0];
        partials[pid * 3 + 1] = red[0][1] + red[1][1] + red[2][1] + red[3][1];
        partials[pid * 3 + 2] = red[0][2] + red[1][2] + red[2][2] + red[3][2];
    }
}

// K2: reduce partials -> mean -> prelu(g@Wc+bc) -> softmax((x@Wc)+bc) -> y (8x3)
__global__ __launch_bounds__(256) void k2_gate(
    const float* __restrict__ partials,
    const float* __restrict__ Wc, const float* __restrict__ bc, const float* __restrict__ ag,
    float* __restrict__ y)
{
    const int b = blockIdx.x;
    const int tid = threadIdx.x;
    float s0 = 0.f, s1 = 0.f, s2 = 0.f;
    for (int i = tid; i < 1024; i += 256) {
        const float* p = partials + (b * 1024 + i) * 3;
        s0 += p[0]; s1 += p[1]; s2 += p[2];
    }
    #pragma unroll
    for (int off = 32; off > 0; off >>= 1) {
        s0 += __shfl_down(s0, off);
        s1 += __shfl_down(s1, off);
        s2 += __shfl_down(s2, off);
    }
    __shared__ float red[4][3];
    const int lane = tid & 63, wave = tid >> 6;
    if (lane == 0) { red[wave][0] = s0; red[wave][1] = s1; red[wave][2] = s2; }
    __syncthreads();
    if (tid == 0) {
        const float inv_n = 1.f / (float)(HW * HW);
        const float g0 = (red[0][0] + red[1][0] + red[2][0] + red[3][0]) * inv_n;
        const float g1 = (red[0][1] + red[1][1] + red[2][1] + red[3][1]) * inv_n;
        const float g2 = (red[0][2] + red[1][2] + red[2][2] + red[3][2]) * inv_n;
        const float x0 = prelu(g0 * Wc[0] + g1 * Wc[3] + g2 * Wc[6] + bc[0], ag[0]);
        const float x1 = prelu(g0 * Wc[1] + g1 * Wc[4] + g2 * Wc[7] + bc[1], ag[1]);
        const float x2 = prelu(g0 * Wc[2] + g1 * Wc[5] + g2 * Wc[8] + bc[2], ag[2]);
        const float q0 = x0 * Wc[0] + x1 * Wc[3] + x2 * Wc[6] + bc[0];
        const float q1 = x0 * Wc[1] + x1 * Wc[4] + x2 * Wc[7] + bc[1];
        const float q2 = x0 * Wc[2] + x1 * Wc[5] + x2 * Wc[8] + bc[2];
        const float m = fmaxf(q0, fmaxf(q1, q2));
        const float e0 = expf(q0 - m), e1 = expf(q1 - m), e2 = expf(q2 - m);
        const float inv = 1.f / (e0 + e1 + e2);
        y[b * 3 + 0] = e0 * inv;
        y[b * 3 + 1] = e1 * inv;
        y[b * 3 + 2] = e2 * inv;
    }
}

// K3: out[i] *= y[b][c], float4 vectorized, in place on d_out.
__global__ __launch_bounds__(256) void k3_scale(float* __restrict__ out, const float* __restrict__ y)
{
    const int i = blockIdx.x * 256 + threadIdx.x;       // float4 index, 1572864 total
    const int f = i * 4;                                 // flat float index
    const int b = f / (HW * HW * 3);
    const int c0 = f % 3;                                // (f % 786432) % 3 == f % 3
    const float* yb = y + b * 3;
    const float m0 = yb[c0];                             // channel c0
    const float m1 = yb[c0 == 2 ? 0 : c0 + 1];           // channel (c0+1)%3
    const float m2 = yb[c0 == 0 ? 2 : c0 - 1];           // channel (c0+2)%3  [was the bug]
    float4 v = reinterpret_cast<float4*>(out)[i];
    v.x *= m0; v.y *= m1; v.z *= m2; v.w *= m0;
    reinterpret_cast<float4*>(out)[i] = v;
}

extern "C" void kernel_launch(void* const* d_in, const int* in_sizes, int n_in,
                              void* d_out, int out_size, void* d_ws, size_t ws_size,
                              hipStream_t stream)
{
    const float* in1 = (const float*)d_in[0];
    const float* in2 = (const float*)d_in[1];
    const float* in3 = (const float*)d_in[2];
    const float* Wd  = (const float*)d_in[3];
    const float* bd  = (const float*)d_in[4];
    const float* ad  = (const float*)d_in[5];
    const float* Wu  = (const float*)d_in[6];
    const float* bu  = (const float*)d_in[7];
    const float* au  = (const float*)d_in[8];
    const float* Wc  = (const float*)d_in[9];
    const float* bc  = (const float*)d_in[10];
    const float* ag  = (const float*)d_in[11];
    float* out = (float*)d_out;

    float* partials = (float*)d_ws;                  // 8192 * 3 floats
    float* y        = partials + 8192 * 3;           // 24 floats

    k1_compute_s<<<dim3(32, 32, NB), 256, 0, stream>>>(in1, in2, in3, Wd, bd, ad, Wu, bu, au, out, partials);
    k2_gate<<<NB, 256, 0, stream>>>(partials, Wc, bc, ag, y);
    k3_scale<<<6144, 256, 0, stream>>>(out, y);
}